// Round 1
// baseline (317.487 us; speedup 1.0000x reference)
//
#include <hip/hip_runtime.h>

#define NCH   256
#define NPROT 320
#define HW    16384      // 128*128
#define TAU   20.0f
#define EPSN  1e-4f

// ---------------------------------------------------------------------------
// Kernel 1a: avg-pool sup_x (5,256,128,128) over 16x16 blocks
//            -> praw[p][c], p = s*64 + gy*8 + gx   (320 x 256 fp32)
// One block per (s,c) plane; coalesced float4 reads; 4-lane shuffle + LDS atomics.
// ---------------------------------------------------------------------------
__global__ __launch_bounds__(256) void k_pool(const float* __restrict__ sup_x,
                                              float* __restrict__ praw) {
    int b = blockIdx.x;            // s*256 + c
    int s = b >> 8;
    int c = b & 255;
    const float4* plane = (const float4*)(sup_x + (size_t)b * HW);
    __shared__ float cell[64];
    int t = threadIdx.x;
    if (t < 64) cell[t] = 0.f;
    __syncthreads();
    for (int i = 0; i < 16; ++i) {
        int f4 = i * 256 + t;      // float4 index in plane, 0..4095
        float4 v = plane[f4];
        float sum = v.x + v.y + v.z + v.w;
        // lanes 4k..4k+3 cover one 16-float row segment -> same grid cell
        sum += __shfl_xor(sum, 1);
        sum += __shfl_xor(sum, 2);
        if ((t & 3) == 0) {
            int h  = f4 >> 5;       // row (32 float4 per row)
            int w4 = f4 & 31;
            int cl = (h >> 4) * 8 + (w4 >> 2);
            atomicAdd(&cell[cl], sum);
        }
    }
    __syncthreads();
    if (t < 64) {
        praw[(size_t)(s * 64 + t) * NCH + c] = cell[t] * (1.0f / 256.0f);
    }
}

// ---------------------------------------------------------------------------
// Kernel 1b: per-proto center (over channels) + safe-normalize.
// Writes PT transposed for the main loop: PT[(c>>2)*NPROT*4 + p*4 + (c&3)]
//   i.e. as float4: PT4[cb*NPROT + p] = channels 4cb..4cb+3 of proto p.
// Also sp[p] = sum_c pro_n[p][c]  (query-centering fold).
// ---------------------------------------------------------------------------
__global__ __launch_bounds__(256) void k_norm(const float* __restrict__ praw,
                                              float* __restrict__ PT,
                                              float* __restrict__ sp) {
    int p = blockIdx.x;
    int c = threadIdx.x;
    __shared__ float red[256];
    float v = praw[p * NCH + c];
    red[c] = v; __syncthreads();
    for (int s = 128; s > 0; s >>= 1) { if (c < s) red[c] += red[c + s]; __syncthreads(); }
    float mean = red[0] * (1.0f / 256.0f);
    __syncthreads();
    float cen = v - mean;
    red[c] = cen * cen; __syncthreads();
    for (int s = 128; s > 0; s >>= 1) { if (c < s) red[c] += red[c + s]; __syncthreads(); }
    float inv = 1.0f / fmaxf(sqrtf(red[0]), EPSN);
    __syncthreads();
    float pn = cen * inv;
    PT[(size_t)(c >> 2) * NPROT * 4 + p * 4 + (c & 3)] = pn;
    red[c] = pn; __syncthreads();
    for (int s = 128; s > 0; s >>= 1) { if (c < s) red[c] += red[c + s]; __syncthreads(); }
    if (c == 0) sp[p] = red[0];
}

// ---------------------------------------------------------------------------
// Kernel 2: fused  normalize(qry) -> 320 dots -> softmax-weighted mean + argmax
// Block = 256 threads, 32 pixels/block. qlds[32][260] fp32 (260 = 4-aligned pad).
// Thread t: pixel = t&31, slot = t>>5 (8 slots x 40 protos, slot order == proto
// order so first-occurrence argmax tie-breaking matches numpy).
// ---------------------------------------------------------------------------
__global__ __launch_bounds__(256, 4) void k_main(const float* __restrict__ qry,
                                                 const float* __restrict__ PT,
                                                 const float* __restrict__ sp,
                                                 float* __restrict__ out) {
    __shared__ __align__(16) float qlds[32 * 260];
    __shared__ float pm[8][32], psum[8][32], ptt[8][32], pidx[8][32];
    __shared__ float meanv[32], invnv[32];
    int t = threadIdx.x;
    int pixbase = blockIdx.x * 32;

    // ---- stage 32 pixels x 256 channels (coalesced float4 over pixel dim) ----
    {
        int f4 = t & 7;            // which float4-of-pixels (0..7)
        int c0 = t >> 3;           // 0..31
        for (int i = 0; i < 8; ++i) {
            int c = c0 + 32 * i;
            float4 v = *(const float4*)(qry + (size_t)c * HW + pixbase + f4 * 4);
            int px = f4 * 4;
            qlds[(px + 0) * 260 + c] = v.x;
            qlds[(px + 1) * 260 + c] = v.y;
            qlds[(px + 2) * 260 + c] = v.z;
            qlds[(px + 3) * 260 + c] = v.w;
        }
    }
    __syncthreads();

    // ---- per-pixel mean and inverse safe-norm ----
    {
        int pix = t & 31, sub = t >> 5;
        float s1 = 0.f, s2 = 0.f;
        for (int j = 0; j < 32; ++j) {
            float q = qlds[pix * 260 + sub * 32 + j];
            s1 += q; s2 += q * q;
        }
        pm[sub][pix] = s1; psum[sub][pix] = s2;
    }
    __syncthreads();
    if (t < 32) {
        float s1 = 0.f, s2 = 0.f;
        for (int j = 0; j < 8; ++j) { s1 += pm[j][t]; s2 += psum[j][t]; }
        float mean = s1 * (1.0f / 256.0f);
        float n2 = fmaxf(s2 - s1 * mean, 0.f);   // sum (q-mean)^2
        meanv[t] = mean;
        invnv[t] = 1.0f / fmaxf(sqrtf(n2), EPSN);
    }
    __syncthreads();

    // ---- 40 proto dots per thread ----
    int pix = t & 31;
    int slot = t >> 5;
    int pbase = slot * 40;
    float acc[40];
    #pragma unroll
    for (int j = 0; j < 40; ++j) acc[j] = 0.f;

    const float4* P4 = (const float4*)PT;
    const float4* qp = (const float4*)(qlds + pix * 260);   // 260*4 % 16 == 0
    for (int cb = 0; cb < 64; ++cb) {
        float4 qv = qp[cb];
        const float4* prow = P4 + (size_t)cb * NPROT + pbase;  // 40 protos: 640 B window
        #pragma unroll
        for (int j = 0; j < 40; ++j) {
            float4 pv = prow[j];
            acc[j] += qv.x * pv.x + qv.y * pv.y + qv.z * pv.z + qv.w * pv.w;
        }
    }

    // ---- dist, local max/argmax, exp-sums ----
    float mean = meanv[pix], invn = invnv[pix];
    float m = -1e30f; int bi = 0;
    #pragma unroll
    for (int j = 0; j < 40; ++j) {
        float d = TAU * invn * (acc[j] - mean * sp[pbase + j]);
        acc[j] = d;
        if (d > m) { m = d; bi = pbase + j; }
    }
    float S = 0.f, T = 0.f;
    #pragma unroll
    for (int j = 0; j < 40; ++j) {
        float e = __expf(acc[j] - m);
        S += e; T += e * acc[j];
    }
    pm[slot][pix] = m; psum[slot][pix] = S; ptt[slot][pix] = T;
    pidx[slot][pix] = (float)bi;
    __syncthreads();

    // ---- merge 8 slots per pixel (slot order == ascending proto order) ----
    if (t < 32) {
        float gm = -1e30f;
        #pragma unroll
        for (int j = 0; j < 8; ++j) gm = fmaxf(gm, pm[j][t]);
        float Sg = 0.f, Tg = 0.f, bidx = 0.f, bm = -1e30f;
        #pragma unroll
        for (int j = 0; j < 8; ++j) {
            float w = __expf(pm[j][t] - gm);
            Sg += psum[j][t] * w;
            Tg += ptt[j][t] * w;
            if (pm[j][t] > bm) { bm = pm[j][t]; bidx = pidx[j][t]; }
        }
        out[pixbase + t] = Tg / Sg;          // pred_grid
        out[HW + pixbase + t] = bidx;        // debug_assign
    }
}

extern "C" void kernel_launch(void* const* d_in, const int* in_sizes, int n_in,
                              void* d_out, int out_size, void* d_ws, size_t ws_size,
                              hipStream_t stream) {
    const float* qry   = (const float*)d_in[0];   // (1,1,256,128,128)
    const float* sup_x = (const float*)d_in[1];   // (1,5,1,256,128,128)
    // d_in[2] = sup_y (unused), d_in[3] = thresh (unused)
    float* out = (float*)d_out;                   // 16384 pred + 16384 assign

    float* praw = (float*)d_ws;                          // 320*256 fp32
    float* PT   = praw + NPROT * NCH;                    // 320*256 fp32 (transposed)
    float* sp   = PT + NPROT * NCH;                      // 320 fp32

    k_pool<<<5 * 256, 256, 0, stream>>>(sup_x, praw);
    k_norm<<<NPROT, 256, 0, stream>>>(praw, PT, sp);
    k_main<<<HW / 32, 256, 0, stream>>>(qry, PT, sp, out);
}

// Round 2
// 193.230 us; speedup vs baseline: 1.6431x; 1.6431x over previous
//
#include <hip/hip_runtime.h>

#define NCH   256
#define NPROT 320
#define HW    16384      // 128*128
#define TAU   20.0f
#define EPSN  1e-4f

// ---------------------------------------------------------------------------
// Kernel 1a: avg-pool sup_x (5,256,128,128) over 16x16 cells -> praw[p][c]
// One block per (s,c) plane. Fully coalesced float4 reads; no atomics:
// for thread t at iteration i, cell column C=(t&31)>>2 is FIXED and cell row
// is i>>1, so each thread accumulates 8 per-cell partials in registers.
// ---------------------------------------------------------------------------
__global__ __launch_bounds__(256) void k_pool(const float* __restrict__ sup_x,
                                              float* __restrict__ praw) {
    int b = blockIdx.x;            // s*256 + c
    int t = threadIdx.x;
    const float4* plane = (const float4*)(sup_x + (size_t)b * HW);
    float rsum[8];
    #pragma unroll
    for (int r = 0; r < 8; ++r) rsum[r] = 0.f;
    #pragma unroll
    for (int i = 0; i < 16; ++i) {
        float4 v = plane[i * 256 + t];          // h = i*8 + (t>>5), w4 = t&31
        rsum[i >> 1] += v.x + v.y + v.z + v.w;  // cell row R = h>>4 = i>>1
    }
    __shared__ float part[8][256];
    #pragma unroll
    for (int r = 0; r < 8; ++r) part[r][t] = rsum[r];
    __syncthreads();
    // cell (R,C) = sum over a in [0,8), bsub in [0,4) of part[R][a*32 + 4C + bsub]
    int R  = t >> 5;
    int cw = t & 31;               // = C*4 + bsub
    float s = 0.f;
    #pragma unroll
    for (int a = 0; a < 8; ++a) s += part[R][a * 32 + cw];
    s += __shfl_xor(s, 1);
    s += __shfl_xor(s, 2);
    if ((t & 3) == 0) {
        int shot = b >> 8, c = b & 255;
        int p = shot * 64 + R * 8 + (cw >> 2);
        praw[(size_t)p * NCH + c] = s * (1.0f / 256.0f);
    }
}

// ---------------------------------------------------------------------------
// Kernel 1b: per-proto center + safe-normalize; PT transposed (float4 per
// 4-channel block, proto-major within block); sp[p] = sum_c pro_n[p][c].
// Shuffle-based block reductions (no log-step LDS ladders).
// ---------------------------------------------------------------------------
__device__ __forceinline__ float block_sum256(float x, float* ws4, int t) {
    #pragma unroll
    for (int o = 1; o < 64; o <<= 1) x += __shfl_xor(x, o);
    if ((t & 63) == 0) ws4[t >> 6] = x;
    __syncthreads();
    float r = ws4[0] + ws4[1] + ws4[2] + ws4[3];
    __syncthreads();
    return r;
}

__global__ __launch_bounds__(256) void k_norm(const float* __restrict__ praw,
                                              float* __restrict__ PT,
                                              float* __restrict__ sp) {
    int p = blockIdx.x;
    int c = threadIdx.x;
    __shared__ float ws4[4];
    float v = praw[p * NCH + c];
    float mean = block_sum256(v, ws4, c) * (1.0f / 256.0f);
    float cen = v - mean;
    float n2 = block_sum256(cen * cen, ws4, c);
    float inv = 1.0f / fmaxf(sqrtf(n2), EPSN);
    float pn = cen * inv;
    PT[(size_t)(c >> 2) * NPROT * 4 + p * 4 + (c & 3)] = pn;
    float ssum = block_sum256(pn, ws4, c);
    if (c == 0) sp[p] = ssum;
}

// ---------------------------------------------------------------------------
// Kernel 2: fused normalize(qry) -> 320 dots -> softmax-weighted mean + argmax
// 32 pixels/block, 256 threads = 4 waves. Wave w owns pixels w*8..w*8+7;
// lane l owns protos {l + 64j, j=0..4} (interleaved -> coalesced PT loads).
// Per cb (4 channels): 5 coalesced global float4 p-loads (L1/L2-served,
// reused across 8 pixels) + 8 broadcast LDS q-reads + 160 FMAs.
// ---------------------------------------------------------------------------
__global__ __launch_bounds__(256, 2) void k_main(const float* __restrict__ qry,
                                                 const float* __restrict__ PT,
                                                 const float* __restrict__ sp,
                                                 float* __restrict__ out) {
    // smem phases:
    //  phase A (staging + FMA): [0..8320) = qlds 32 x 260
    //                           [8320..8576) pm1, [8576..8832) ps1
    //  phase B (merge, after FMA): M/S/T/I: 4 arrays 32 x 65 at 0,2080,4160,6240
    //                              P2 m/s/t/i: 4 arrays 32 x 9 at 8320 + k*288
    __shared__ __align__(16) float smem[9472];
    __shared__ float meanv[32], invnv[32];
    int t = threadIdx.x;
    int pixbase = blockIdx.x * 32;

    // ---- stage 32 pixels x 256 channels (coalesced float4 over pixel dim) ----
    {
        int f4 = t & 7;            // which float4-of-pixels (0..7)
        int c0 = t >> 3;           // 0..31
        #pragma unroll
        for (int i = 0; i < 8; ++i) {
            int c = c0 + 32 * i;
            float4 v = *(const float4*)(qry + (size_t)c * HW + pixbase + f4 * 4);
            int px = f4 * 4;
            smem[(px + 0) * 260 + c] = v.x;
            smem[(px + 1) * 260 + c] = v.y;
            smem[(px + 2) * 260 + c] = v.z;
            smem[(px + 3) * 260 + c] = v.w;
        }
    }
    __syncthreads();

    // ---- per-pixel mean and inverse safe-norm ----
    {
        int pix = t & 31, sub = t >> 5;
        float s1 = 0.f, s2 = 0.f;
        #pragma unroll
        for (int j = 0; j < 32; ++j) {
            float q = smem[pix * 260 + sub * 32 + j];
            s1 += q; s2 += q * q;
        }
        smem[8320 + sub * 32 + pix] = s1;
        smem[8576 + sub * 32 + pix] = s2;
    }
    __syncthreads();
    if (t < 32) {
        float s1 = 0.f, s2 = 0.f;
        #pragma unroll
        for (int j = 0; j < 8; ++j) { s1 += smem[8320 + j * 32 + t]; s2 += smem[8576 + j * 32 + t]; }
        float mean = s1 * (1.0f / 256.0f);
        float n2 = fmaxf(s2 - s1 * mean, 0.f);   // sum (q-mean)^2
        meanv[t] = mean;
        invnv[t] = 1.0f / fmaxf(sqrtf(n2), EPSN);
    }
    __syncthreads();

    // ---- register-tiled dot products: 8 pixels x 5 protos per thread ----
    int lane = t & 63;
    int w = t >> 6;
    float acc[8][5];
    #pragma unroll
    for (int i = 0; i < 8; ++i)
        #pragma unroll
        for (int j = 0; j < 5; ++j) acc[i][j] = 0.f;

    {
        const float4* pptr = (const float4*)PT + lane;
        const float* qbase = smem + w * 8 * 260;
        for (int cb = 0; cb < 64; ++cb) {
            float4 pv0 = pptr[0];
            float4 pv1 = pptr[64];
            float4 pv2 = pptr[128];
            float4 pv3 = pptr[192];
            float4 pv4 = pptr[256];
            #pragma unroll
            for (int i = 0; i < 8; ++i) {
                float4 qv = *(const float4*)(qbase + i * 260);
                acc[i][0] = fmaf(qv.x, pv0.x, acc[i][0]);
                acc[i][0] = fmaf(qv.y, pv0.y, acc[i][0]);
                acc[i][0] = fmaf(qv.z, pv0.z, acc[i][0]);
                acc[i][0] = fmaf(qv.w, pv0.w, acc[i][0]);
                acc[i][1] = fmaf(qv.x, pv1.x, acc[i][1]);
                acc[i][1] = fmaf(qv.y, pv1.y, acc[i][1]);
                acc[i][1] = fmaf(qv.z, pv1.z, acc[i][1]);
                acc[i][1] = fmaf(qv.w, pv1.w, acc[i][1]);
                acc[i][2] = fmaf(qv.x, pv2.x, acc[i][2]);
                acc[i][2] = fmaf(qv.y, pv2.y, acc[i][2]);
                acc[i][2] = fmaf(qv.z, pv2.z, acc[i][2]);
                acc[i][2] = fmaf(qv.w, pv2.w, acc[i][2]);
                acc[i][3] = fmaf(qv.x, pv3.x, acc[i][3]);
                acc[i][3] = fmaf(qv.y, pv3.y, acc[i][3]);
                acc[i][3] = fmaf(qv.z, pv3.z, acc[i][3]);
                acc[i][3] = fmaf(qv.w, pv3.w, acc[i][3]);
                acc[i][4] = fmaf(qv.x, pv4.x, acc[i][4]);
                acc[i][4] = fmaf(qv.y, pv4.y, acc[i][4]);
                acc[i][4] = fmaf(qv.z, pv4.z, acc[i][4]);
                acc[i][4] = fmaf(qv.w, pv4.w, acc[i][4]);
            }
            pptr += NPROT;
            qbase += 4;
        }
    }

    // ---- per-thread softmax partials over its 5 protos, per pixel ----
    float spv[5];
    #pragma unroll
    for (int j = 0; j < 5; ++j) spv[j] = sp[lane + 64 * j];

    float m8[8], S8[8], T8[8], I8[8];
    #pragma unroll
    for (int i = 0; i < 8; ++i) {
        int pix = w * 8 + i;
        float mean = meanv[pix], invn = invnv[pix];
        float d[5];
        float m = -1e30f; int bj = 0;
        #pragma unroll
        for (int j = 0; j < 5; ++j) {
            d[j] = TAU * invn * (acc[i][j] - mean * spv[j]);
            if (d[j] > m) { m = d[j]; bj = j; }
        }
        float S = 0.f, T = 0.f;
        #pragma unroll
        for (int j = 0; j < 5; ++j) {
            float e = __expf(d[j] - m);
            S += e; T += e * d[j];
        }
        m8[i] = m; S8[i] = S; T8[i] = T; I8[i] = (float)(lane + 64 * bj);
    }
    __syncthreads();   // everyone done reading qlds; safe to alias

    float* M  = smem;
    float* Sa = smem + 2080;
    float* Ta = smem + 4160;
    float* Ia = smem + 6240;
    #pragma unroll
    for (int i = 0; i < 8; ++i) {
        int pix = w * 8 + i;
        M [pix * 65 + lane] = m8[i];
        Sa[pix * 65 + lane] = S8[i];
        Ta[pix * 65 + lane] = T8[i];
        Ia[pix * 65 + lane] = I8[i];
    }
    __syncthreads();

    // ---- stage 2: merge 8 lanes per (pixel, octant) ----
    float* P2m = smem + 8320;
    float* P2s = smem + 8608;
    float* P2t = smem + 8896;
    float* P2i = smem + 9184;
    {
        int pix = t >> 3, oct = t & 7;
        int base = pix * 65 + oct * 8;
        float gm = -1e30f;
        #pragma unroll
        for (int k = 0; k < 8; ++k) gm = fmaxf(gm, M[base + k]);
        float S = 0.f, T = 0.f, bi = 0.f, bm = -1e30f;
        #pragma unroll
        for (int k = 0; k < 8; ++k) {
            float mk = M[base + k];
            float wg = __expf(mk - gm);
            S += Sa[base + k] * wg;
            T += Ta[base + k] * wg;
            if (mk > bm) { bm = mk; bi = Ia[base + k]; }
        }
        P2m[pix * 9 + oct] = gm;
        P2s[pix * 9 + oct] = S;
        P2t[pix * 9 + oct] = T;
        P2i[pix * 9 + oct] = bi;
    }
    __syncthreads();

    // ---- stage 3: merge 8 octants, write out ----
    if (t < 32) {
        float gm = -1e30f;
        #pragma unroll
        for (int k = 0; k < 8; ++k) gm = fmaxf(gm, P2m[t * 9 + k]);
        float S = 0.f, T = 0.f, bi = 0.f, bm = -1e30f;
        #pragma unroll
        for (int k = 0; k < 8; ++k) {
            float mk = P2m[t * 9 + k];
            float wg = __expf(mk - gm);
            S += P2s[t * 9 + k] * wg;
            T += P2t[t * 9 + k] * wg;
            if (mk > bm) { bm = mk; bi = P2i[t * 9 + k]; }
        }
        out[pixbase + t] = T / S;           // pred_grid
        out[HW + pixbase + t] = bi;         // debug_assign
    }
}

extern "C" void kernel_launch(void* const* d_in, const int* in_sizes, int n_in,
                              void* d_out, int out_size, void* d_ws, size_t ws_size,
                              hipStream_t stream) {
    const float* qry   = (const float*)d_in[0];   // (1,1,256,128,128)
    const float* sup_x = (const float*)d_in[1];   // (1,5,1,256,128,128)
    float* out = (float*)d_out;                   // 16384 pred + 16384 assign

    float* praw = (float*)d_ws;                          // 320*256 fp32
    float* PT   = praw + NPROT * NCH;                    // 320*256 fp32 (transposed)
    float* sp   = PT + NPROT * NCH;                      // 320 fp32

    k_pool<<<5 * 256, 256, 0, stream>>>(sup_x, praw);
    k_norm<<<NPROT, 256, 0, stream>>>(praw, PT, sp);
    k_main<<<HW / 32, 256, 0, stream>>>(qry, PT, sp, out);
}